// Round 9
// baseline (324.584 us; speedup 1.0000x reference)
//
#include <hip/hip_runtime.h>
#include <hip/hip_bf16.h>

// SegmentDeactivation: KAN layer folded into one bf16 GEMM.
// K = 512*36 (dense-ified 4-sparse cubic B-spline bases) + 512 (silu(x)·W_base)
//   + 512 (x·masked-slope) = 19456 = 38*512. bias = sum of masked intercepts.
// R9: TWO dispatches total. prep = pack_b (per-block mask-dtype detect,
//     block-reduced bias stores) + basis precompute + cnt zero. gemm = R8
//     structure + PB register prefetch (1 iter ahead) + fused last-block
//     finisher reduce (threadfence + device atomic counter per tile).

typedef unsigned short u16;
typedef unsigned int u32;
typedef unsigned long long u64;
typedef __attribute__((ext_vector_type(8))) short short8;
typedef __attribute__((ext_vector_type(4))) float floatx4;
typedef __attribute__((ext_vector_type(4))) unsigned int uintx4;

#define IN_F 512
#define OUT_F 512
#define BATCH 1024
#define K_SPLINE (IN_F * 36)            // 18432
#define K_BASE_OFF K_SPLINE
#define K_LIN_OFF (K_SPLINE + IN_F)
#define K_TOT (K_SPLINE + 2 * IN_F)     // 19456 = 38*512
#define SPLITS 38
#define KPS 512
#define KIT 8                           // KPS/64
#define MN (BATCH * OUT_F)

static __device__ inline u16 f2b(float f) {
  union { float f; u32 u; } v; v.f = f;
  u32 r = v.u + 0x7FFFu + ((v.u >> 16) & 1u);  // round-nearest-even
  return (u16)(r >> 16);
}
static __device__ inline float b2f(u32 lo16) {  // bf16 bits (low 16) -> float
  union { u32 u; float f; } v; v.u = lo16 << 16; return v.f;
}

// ---- prep: blocks 0..1023 = pack_b (one o-half each, per-block mask detect,
//      bias block-reduce store, blk0 zeroes tile counters);
//      blocks 1024..3071 = per-(b,i) basis -> PB8 ([b][i] layout).
__global__ __launch_bounds__(256) void prep_kernel(
    const float* __restrict__ bw, const float* __restrict__ sw,
    const float* __restrict__ sc, const void* __restrict__ maskp,
    const float* __restrict__ x, u16* __restrict__ B,
    float* __restrict__ bias_part, u64* __restrict__ PB8, int* __restrict__ cnt) {
  __shared__ u64 lds64[1120 * 4];  // 35840B: float stage, reused as u16 rows
  __shared__ int sflag;
  __shared__ float ws4[4];
  int blk = blockIdx.x, t = threadIdx.x;

  if (blk >= 1024) {
    // ---- basis precompute: id = b*512 + i
    int id = (blk - 1024) * 256 + t;
    float xv = x[id];
    int mc = (int)floorf((xv + 1.1875f) * 16.0f);
    float gm = (float)mc * 0.0625f - 1.1875f;
    if (xv < gm) { mc -= 1; gm -= 0.0625f; }
    else if (xv >= gm + 0.0625f) { mc += 1; gm += 0.0625f; }
    u32 lo, hi;
    if (mc >= 0 && mc <= 37) {
      float t_ = (xv - gm) * 16.0f;
      float t2 = t_ * t_, t3 = t2 * t_;
      float omt = 1.0f - t_;
      u16 r0 = f2b(omt * omt * omt * (1.0f / 6.0f));
      u16 r1 = f2b((3.0f * t3 - 6.0f * t2 + 4.0f) * (1.0f / 6.0f));
      u16 r2 = f2b((-3.0f * t3 + 3.0f * t2 + 3.0f * t_ + 1.0f) * (1.0f / 6.0f));
      lo = (u32)r0 | ((u32)r1 << 16);
      hi = (u32)r2 | ((u32)mc << 16);
    } else {
      lo = 0; hi = 0xFFFF0000u;              // sentinel cell -> all writes dead
    }
    PB8[id] = (u64)lo | ((u64)hi << 32);
    return;
  }

  // ---- pack_b: id = o*512+i, o = blk>>1
  if (blk == 0 && t < 32) cnt[t] = 0;
  float* lds_f = (float*)lds64;
  u16* lds_u = (u16*)lds64;
  int id = blk * 256 + t;
  int o = id >> 9, i = id & 511;
  int i0 = (blk & 1) * 256;

  const float* swb = sw + ((size_t)o * 512 + i0) * 35;
#pragma unroll
  for (int j = 0; j < 35; ++j) lds_f[j * 256 + t] = swb[j * 256 + t];

  // per-block mask dtype detect over THIS block's entries only.
  // uint8 window: words [blk*64,+64) == bytes [blk*256,+256). Safe for all dtypes.
  const u32* mw = (const u32*)maskp;
  if (t == 0) sflag = 0;
  __syncthreads();
  if (t < 64) {
    u32 w2 = mw[blk * 64 + t];
    // uint8 evidence: high bytes set but not the f32 1.0f pattern
    if ((w2 & 0xFFFFFF00u) && w2 != 0x3F800000u) atomicOr(&sflag, 1);
  }
  __syncthreads();
  int fl = sflag;
  if (!(fl & 1)) {
    // buffer is >= 1MB (int32 or f32): words [blk*256,+256) are this block's entries
    u32 w1 = mw[blk * 256 + t];
    if (w1 == 0x3F800000u) atomicOr(&sflag, 2);
  }
  __syncthreads();
  fl = sflag;
  bool mk;
  if (fl & 1)      mk = ((const unsigned char*)maskp)[id] != 0;
  else if (fl & 2) mk = ((const float*)maskp)[id] != 0.0f;
  else             mk = ((const int*)maskp)[id] != 0;

  float s = sc[id];
  float w[35];
#pragma unroll
  for (int c = 0; c < 35; ++c) w[c] = lds_f[t * 35 + c] * s;
  __syncthreads();

  // linear fallback params from endpoint spline values (dx = 2 exactly)
  float ys = (w[0] + 4.0f * w[1] + w[2]) * (1.0f / 6.0f);
  float ye = (w[32] + 4.0f * w[33] + w[34]) * (1.0f / 6.0f);
  float a = (ye - ys) * 0.5f;
  float bl = ys + a;

#pragma unroll
  for (int c = 0; c < 35; ++c) lds_u[t * 36 + c] = f2b(mk ? 0.0f : w[c]);
  lds_u[t * 36 + 35] = 0;

  B[(size_t)o * K_TOT + K_BASE_OFF + i] = f2b(bw[id]);
  B[(size_t)o * K_TOT + K_LIN_OFF + i] = f2b(mk ? a : 0.0f);

  // bias block-reduce: sum of (mk ? bl : 0) over this block's 256 i's
  float v = mk ? bl : 0.0f;
#pragma unroll
  for (int off = 32; off >= 1; off >>= 1) v += __shfl_down(v, off);
  if ((t & 63) == 0) ws4[t >> 6] = v;
  __syncthreads();
  if (t == 0) bias_part[blk] = ws4[0] + ws4[1] + ws4[2] + ws4[3];

  u64* dst = (u64*)(B + (size_t)o * K_TOT + (size_t)i0 * 36);
#pragma unroll
  for (int j = 0; j < 9; ++j) dst[j * 256 + t] = lds64[j * 256 + t];
}

// ---- fused GEMM + finisher reduce. 128x128 tile, BK=64, 16x16x32 bf16 MFMA,
// grid 1216: ks = id>>5 (0..37), tile = id&31. Thread-owned A-build with PB
// register prefetch one iter ahead; last block per tile reduces 38 bf16
// partials + bias -> fp32 out.
__global__ __launch_bounds__(256, 4) void gemm_fused(const float* __restrict__ x,
                                                     const u64* __restrict__ PB8,
                                                     const u16* __restrict__ Bp,
                                                     u16* __restrict__ P,
                                                     int* __restrict__ cnt,
                                                     const float* __restrict__ bias_part,
                                                     float* __restrict__ out) {
  __shared__ u16 As[128 * 64 + 64];  // +64 u16 dummy pad for dead scatter lanes
  __shared__ u16 Bs[128 * 64];
  __shared__ int lastFlag;

  int t = threadIdx.x;
  int id = blockIdx.x;
  int ks = id >> 5, tile = id & 31;
  int bm = tile >> 2, bn = tile & 3;
  int w = t >> 6, l = t & 63;
  int wm = w & 1, wn = w >> 1;

  floatx4 acc[4][4];
#pragma unroll
  for (int p = 0; p < 4; ++p)
#pragma unroll
    for (int q = 0; q < 4; ++q) acc[p][q] = (floatx4)0.0f;

  int k0s = ks * KPS;
  bool spline = (ks < 36);

  // B staging params (XOR-swizzled chunks, wave-uniform-base + lane*16 dest)
  int ra = t >> 3;
  int cg = (t & 7) ^ (ra & 7);
  const u16* Bg = Bp + (size_t)(bn * 128 + ra) * K_TOT + k0s + cg * 8;
  u16* Bsp = Bs + t * 8;

  // A-build ownership: row rr_, col half hf (32 cols)
  int rr_ = t >> 1, hf = t & 1;
  int rx7 = rr_ & 7;
  int dummy = 128 * 64 + (t & 63);
  const u64* PBrow = PB8 + (size_t)(bm * 128 + rr_) * IN_F;

  int mr = l & 15;
  int cq = l >> 4;

  // PB prefetch state (one iter ahead)
  int if_cur = 0; u64 e0 = 0, e1 = 0;
  if (spline) {
    if_cur = (k0s + hf * 32) / 36;
    e0 = PBrow[if_cur];
    e1 = PBrow[if_cur + 1];   // may read 1 past row end: unused then, in-ws.
  }

  for (int kk = 0; kk < KIT; ++kk) {
    // issue B loads first; drain overlapped by A-build below
#pragma unroll
    for (int p = 0; p < 4; ++p)
      __builtin_amdgcn_global_load_lds(
          (const __attribute__((address_space(1))) void*)(Bg + (size_t)p * 32 * K_TOT),
          (__attribute__((address_space(3))) void*)(Bsp + p * 2048), 16, 0, 0);
    Bg += 64;

    int if_nxt = if_cur; u64 en0 = e0, en1 = e1;
    if (spline) {
      // zero own 32-col half (4 x b128, swizzled chunks)
#pragma unroll
      for (int q = 0; q < 4; ++q) {
        int ch = hf * 4 + q;
        *(uintx4*)&As[rr_ * 64 + ((ch ^ rx7) << 3)] = (uintx4)0u;
      }
      int k0 = k0s + kk * 64;
      int k0w = k0 + hf * 32;
      int i_last = (k0w + 31) / 36;
      // scatter the (<=2) prefetched PB entries into own half
#pragma unroll
      for (int ii = 0; ii < 2; ++ii) {
        int i = if_cur + ii;
        if (i <= i_last) {
          u64 e = ii ? e1 : e0;
          u32 lo = (u32)e, hi = (u32)(e >> 32);
          int mc = (int)(hi >> 16);
          float f0 = b2f(lo & 0xFFFFu);
          float f1 = b2f(lo >> 16);
          float f2 = b2f(hi & 0xFFFFu);
          u16 bv[4] = {(u16)lo, (u16)(lo >> 16), (u16)hi, f2b(1.0f - f0 - f1 - f2)};
          int cb = i * 36 + mc - 3 - k0;   // local col of j=0 within 64-window
#pragma unroll
          for (int j = 0; j < 4; ++j) {
            int c = cb + j;
            bool ok = ((u32)(c - hf * 32) < 32u) && ((u32)(mc - 3 + j) < 35u);
            int addr = ok ? (rr_ * 64 + (((c >> 3) ^ rx7) << 3) + (c & 7)) : dummy;
            As[addr] = bv[j];
          }
        }
      }
      // prefetch PB for next iter (latency hides under barrier+MFMA)
      if (kk + 1 < KIT) {
        if_nxt = (k0w + 64) / 36;
        en0 = PBrow[if_nxt];
        en1 = PBrow[if_nxt + 1];
      }
    } else {
      // ks==36: silu(x); ks==37: x. Full 64-col fill, no zero pass.
      bool isBase = (ks == 36);
      int xb = kk * 64;
#pragma unroll
      for (int p = 0; p < 4; ++p) {
        int cid = t + 256 * p;       // (row, chunk)
        int row = cid >> 3, ch = cid & 7;
        const float* xp = &x[(size_t)(bm * 128 + row) * IN_F + xb + ch * 8];
        floatx4 v0 = *(const floatx4*)xp;
        floatx4 v1 = *(const floatx4*)(xp + 4);
        float f[8] = {v0.x, v0.y, v0.z, v0.w, v1.x, v1.y, v1.z, v1.w};
        u16 r[8];
#pragma unroll
        for (int j = 0; j < 8; ++j) {
          float vv = f[j];
          if (isBase) vv = vv / (1.0f + __expf(-vv));
          r[j] = f2b(vv);
        }
        *(short8*)(As + row * 64 + ((ch ^ (row & 7)) << 3)) = *(short8*)r;
      }
    }
    __syncthreads();   // As written + Bs landed (vmcnt drain overlapped by build)

    // MFMA phase
#pragma unroll
    for (int h = 0; h < 2; ++h) {
      short8 af[4], bf[4];
      int c = h * 4 + cq;
#pragma unroll
      for (int tm = 0; tm < 4; ++tm) {
        int row = wm * 64 + tm * 16 + mr;
        af[tm] = *(const short8*)&As[row * 64 + ((c ^ (row & 7)) << 3)];
      }
#pragma unroll
      for (int tn = 0; tn < 4; ++tn) {
        int row = wn * 64 + tn * 16 + mr;
        bf[tn] = *(const short8*)&Bs[row * 64 + ((c ^ (row & 7)) << 3)];
      }
#pragma unroll
      for (int tm = 0; tm < 4; ++tm)
#pragma unroll
        for (int tn = 0; tn < 4; ++tn)
          acc[tm][tn] = __builtin_amdgcn_mfma_f32_16x16x32_bf16(af[tm], bf[tn], acc[tm][tn], 0, 0, 0);
    }
    __syncthreads();   // MFMA reads done before next iter overwrites
    if_cur = if_nxt; e0 = en0; e1 = en1;
  }

  // ---- epilogue: direct coalesced bf16 partial store, fixed per-thread layout.
  u16* Pb = P + ((size_t)tile * SPLITS + ks) * 16384;
#pragma unroll
  for (int q = 0; q < 8; ++q) {
    int tm = q >> 1, tn0 = (q & 1) * 2;
    u16 r[8];
#pragma unroll
    for (int z = 0; z < 4; ++z) r[z] = f2b(acc[tm][tn0][z]);
#pragma unroll
    for (int z = 0; z < 4; ++z) r[4 + z] = f2b(acc[tm][tn0 + 1][z]);
    *(short8*)(Pb + q * 2048 + t * 8) = *(short8*)r;
  }

  // ---- last-block finisher: reduce 38 partials + bias -> out for this tile
  __threadfence();
  __syncthreads();
  if (t == 0) lastFlag = (atomicAdd(&cnt[tile], 1) == SPLITS - 1);
  __syncthreads();
  if (!lastFlag) return;
  __threadfence();

  const u16* Pt = P + (size_t)tile * SPLITS * 16384;
  int row0b = bm * 128 + wm * 64 + ((l >> 4) << 2);
  int col0b = bn * 128 + wn * 64 + (l & 15);
#pragma unroll
  for (int q = 0; q < 8; ++q) {
    const u16* base = Pt + q * 2048 + t * 8;
    float s[8] = {0, 0, 0, 0, 0, 0, 0, 0};
    for (int k2 = 0; k2 < SPLITS; ++k2) {
      short8 v = *(const short8*)(base + (size_t)k2 * 16384);
#pragma unroll
      for (int j = 0; j < 8; ++j) s[j] += b2f((u32)(u16)v[j]);
    }
    int tm = q >> 1, tn0 = (q & 1) * 2;
#pragma unroll
    for (int j = 0; j < 8; ++j) {
      int tn = tn0 + (j >> 2), rr = j & 3;
      int row = row0b + tm * 16 + rr;
      int col = col0b + tn * 16;
      float bsv = bias_part[2 * col] + bias_part[2 * col + 1];
      out[(size_t)row * OUT_F + col] = s[j] + bsv;
    }
  }
}

extern "C" void kernel_launch(void* const* d_in, const int* in_sizes, int n_in,
                              void* d_out, int out_size, void* d_ws, size_t ws_size,
                              hipStream_t stream) {
  const float* x  = (const float*)d_in[0];
  const float* bw = (const float*)d_in[1];
  const float* sw = (const float*)d_in[2];
  const float* sc = (const float*)d_in[3];
  // d_in[4] = grid: uniform h=1/16 extended knots, constants baked in.
  const void* mask = d_in[5];

  const size_t B_BYTES = (size_t)OUT_F * K_TOT * 2;         // 19,922,944
  const size_t BIAS_OFF = B_BYTES;                          // 1024 floats
  const size_t CNT_OFF = B_BYTES + 4096;                    // 32 ints
  const size_t PB_OFF = B_BYTES + 8192;
  const size_t PB_BYTES = (size_t)MN * 8;                   // 4,194,304
  const size_t P_OFF = PB_OFF + PB_BYTES;                   // P: 39,845,888

  char* wsb = (char*)d_ws;
  u16* Bpack = (u16*)wsb;
  float* bias_part = (float*)(wsb + BIAS_OFF);
  int* cnt = (int*)(wsb + CNT_OFF);
  u64* PB8 = (u64*)(wsb + PB_OFF);
  u16* P = (u16*)(wsb + P_OFF);

  prep_kernel<<<3072, 256, 0, stream>>>(bw, sw, sc, mask, x, Bpack, bias_part, PB8, cnt);
  gemm_fused<<<32 * SPLITS, 256, 0, stream>>>(x, PB8, Bpack, P, cnt, bias_part, (float*)d_out);
}

// Round 10
// 137.831 us; speedup vs baseline: 2.3549x; 2.3549x over previous
//
#include <hip/hip_runtime.h>
#include <hip/hip_bf16.h>

// SegmentDeactivation: KAN layer folded into one bf16 GEMM.
// K = 512*36 (dense-ified 4-sparse cubic B-spline bases) + 512 (silu(x)·W_base)
//   + 512 (x·masked-slope) = 19456. bias = sum of masked intercepts.
// R10: grid EXACTLY 1024 (= 4 blocks/CU x 256 CUs, one co-resident wave, no
//      tail): 32 tiles x 32 splits, uneven KPS (16x640 + 16x576, both /64).
//      Per-iter spline/base branch. Finisher reverted (R9 fence storm);
//      separate reduce. 3 dispatches: prep, gemm, reduce.

typedef unsigned short u16;
typedef unsigned int u32;
typedef unsigned long long u64;
typedef __attribute__((ext_vector_type(8))) short short8;
typedef __attribute__((ext_vector_type(4))) float floatx4;
typedef __attribute__((ext_vector_type(4))) unsigned int uintx4;

#define IN_F 512
#define OUT_F 512
#define BATCH 1024
#define K_SPLINE (IN_F * 36)            // 18432
#define K_BASE_OFF K_SPLINE
#define K_LIN_OFF (K_SPLINE + IN_F)
#define K_TOT (K_SPLINE + 2 * IN_F)     // 19456
#define SPLITS 32                       // 16 x (10*64) + 16 x (9*64)
#define MN (BATCH * OUT_F)

static __device__ inline u16 f2b(float f) {
  union { float f; u32 u; } v; v.f = f;
  u32 r = v.u + 0x7FFFu + ((v.u >> 16) & 1u);  // round-nearest-even
  return (u16)(r >> 16);
}
static __device__ inline float b2f(u32 lo16) {  // bf16 bits (low 16) -> float
  union { u32 u; float f; } v; v.u = lo16 << 16; return v.f;
}

// ---- prep: blocks 0..1023 = pack_b (one o-half each, per-block mask detect,
//      bias block-reduce store); blocks 1024..3071 = per-(b,i) basis -> PB8.
__global__ __launch_bounds__(256) void prep_kernel(
    const float* __restrict__ bw, const float* __restrict__ sw,
    const float* __restrict__ sc, const void* __restrict__ maskp,
    const float* __restrict__ x, u16* __restrict__ B,
    float* __restrict__ bias_part, u64* __restrict__ PB8) {
  __shared__ u64 lds64[1120 * 4];  // 35840B: float stage, reused as u16 rows
  __shared__ int sflag;
  __shared__ float ws4[4];
  int blk = blockIdx.x, t = threadIdx.x;

  if (blk >= 1024) {
    // ---- basis precompute: id = b*512 + i
    int id = (blk - 1024) * 256 + t;
    float xv = x[id];
    int mc = (int)floorf((xv + 1.1875f) * 16.0f);
    float gm = (float)mc * 0.0625f - 1.1875f;
    if (xv < gm) { mc -= 1; gm -= 0.0625f; }
    else if (xv >= gm + 0.0625f) { mc += 1; gm += 0.0625f; }
    u32 lo, hi;
    if (mc >= 0 && mc <= 37) {
      float t_ = (xv - gm) * 16.0f;
      float t2 = t_ * t_, t3 = t2 * t_;
      float omt = 1.0f - t_;
      u16 r0 = f2b(omt * omt * omt * (1.0f / 6.0f));
      u16 r1 = f2b((3.0f * t3 - 6.0f * t2 + 4.0f) * (1.0f / 6.0f));
      u16 r2 = f2b((-3.0f * t3 + 3.0f * t2 + 3.0f * t_ + 1.0f) * (1.0f / 6.0f));
      lo = (u32)r0 | ((u32)r1 << 16);
      hi = (u32)r2 | ((u32)mc << 16);
    } else {
      lo = 0; hi = 0xFFFF0000u;              // sentinel cell -> all writes dead
    }
    PB8[id] = (u64)lo | ((u64)hi << 32);
    return;
  }

  // ---- pack_b: id = o*512+i, o = blk>>1
  float* lds_f = (float*)lds64;
  u16* lds_u = (u16*)lds64;
  int id = blk * 256 + t;
  int o = id >> 9, i = id & 511;
  int i0 = (blk & 1) * 256;

  const float* swb = sw + ((size_t)o * 512 + i0) * 35;
#pragma unroll
  for (int j = 0; j < 35; ++j) lds_f[j * 256 + t] = swb[j * 256 + t];

  // per-block mask dtype detect over THIS block's entries only.
  const u32* mw = (const u32*)maskp;
  if (t == 0) sflag = 0;
  __syncthreads();
  if (t < 64) {
    u32 w2 = mw[blk * 64 + t];   // uint8 window: bytes [blk*256,+256)
    if ((w2 & 0xFFFFFF00u) && w2 != 0x3F800000u) atomicOr(&sflag, 1);
  }
  __syncthreads();
  int fl = sflag;
  if (!(fl & 1)) {
    u32 w1 = mw[blk * 256 + t];  // int32/f32 window: words [blk*256,+256)
    if (w1 == 0x3F800000u) atomicOr(&sflag, 2);
  }
  __syncthreads();
  fl = sflag;
  bool mk;
  if (fl & 1)      mk = ((const unsigned char*)maskp)[id] != 0;
  else if (fl & 2) mk = ((const float*)maskp)[id] != 0.0f;
  else             mk = ((const int*)maskp)[id] != 0;

  float s = sc[id];
  float w[35];
#pragma unroll
  for (int c = 0; c < 35; ++c) w[c] = lds_f[t * 35 + c] * s;
  __syncthreads();

  // linear fallback params from endpoint spline values (dx = 2 exactly)
  float ys = (w[0] + 4.0f * w[1] + w[2]) * (1.0f / 6.0f);
  float ye = (w[32] + 4.0f * w[33] + w[34]) * (1.0f / 6.0f);
  float a = (ye - ys) * 0.5f;
  float bl = ys + a;

#pragma unroll
  for (int c = 0; c < 35; ++c) lds_u[t * 36 + c] = f2b(mk ? 0.0f : w[c]);
  lds_u[t * 36 + 35] = 0;

  B[(size_t)o * K_TOT + K_BASE_OFF + i] = f2b(bw[id]);
  B[(size_t)o * K_TOT + K_LIN_OFF + i] = f2b(mk ? a : 0.0f);

  // bias block-reduce: sum of (mk ? bl : 0) over this block's 256 i's
  float v = mk ? bl : 0.0f;
#pragma unroll
  for (int off = 32; off >= 1; off >>= 1) v += __shfl_down(v, off);
  if ((t & 63) == 0) ws4[t >> 6] = v;
  __syncthreads();
  if (t == 0) bias_part[blk] = ws4[0] + ws4[1] + ws4[2] + ws4[3];

  u64* dst = (u64*)(B + (size_t)o * K_TOT + (size_t)i0 * 36);
#pragma unroll
  for (int j = 0; j < 9; ++j) dst[j * 256 + t] = lds64[j * 256 + t];
}

// ---- fused GEMM: 128x128 tile, BK=64, 16x16x32 bf16 MFMA, grid 1024 exactly.
// id = ks*32 + tile; ks<16 -> 10 iters from ks*640, else 9 iters from
// 10240+(ks-16)*576. Per-iter uniform spline/base branch on k0.
__global__ __launch_bounds__(256, 4) void gemm_fused(const float* __restrict__ x,
                                                     const u64* __restrict__ PB8,
                                                     const u16* __restrict__ Bp,
                                                     u16* __restrict__ P) {
  __shared__ u16 As[128 * 64 + 64];  // +64 u16 dummy pad for dead scatter lanes
  __shared__ u16 Bs[128 * 64];

  int t = threadIdx.x;
  int id = blockIdx.x;
  int ks = id >> 5, tile = id & 31;
  int bm = tile >> 2, bn = tile & 3;
  int w = t >> 6, l = t & 63;
  int wm = w & 1, wn = w >> 1;

  floatx4 acc[4][4];
#pragma unroll
  for (int p = 0; p < 4; ++p)
#pragma unroll
    for (int q = 0; q < 4; ++q) acc[p][q] = (floatx4)0.0f;

  int nit = (ks < 16) ? 10 : 9;
  int k0s = (ks < 16) ? ks * 640 : 10240 + (ks - 16) * 576;

  // B staging params (XOR-swizzled chunks, wave-uniform-base + lane*16 dest)
  int ra = t >> 3;
  int cg = (t & 7) ^ (ra & 7);
  const u16* Bg = Bp + (size_t)(bn * 128 + ra) * K_TOT + k0s + cg * 8;
  u16* Bsp = Bs + t * 8;

  // A-build ownership: row rr_, col half hf (32 cols)
  int rr_ = t >> 1, hf = t & 1;
  int rx7 = rr_ & 7;
  int dummy = 128 * 64 + (t & 63);
  const u64* PBrow = PB8 + (size_t)(bm * 128 + rr_) * IN_F;

  int mr = l & 15;
  int cq = l >> 4;

  // PB prefetch state (one iter ahead, valid when current iter is spline)
  int if_cur = 0; u64 e0 = 0, e1 = 0;
  if (k0s < K_BASE_OFF) {
    if_cur = (k0s + hf * 32) / 36;
    e0 = PBrow[if_cur];
    e1 = PBrow[if_cur + 1];   // may read 1 past row end: unused then, in-ws.
  }

  int k0 = k0s;
  for (int kk = 0; kk < nit; ++kk, k0 += 64) {
    // issue B loads first; drain overlapped by A-build below
#pragma unroll
    for (int p = 0; p < 4; ++p)
      __builtin_amdgcn_global_load_lds(
          (const __attribute__((address_space(1))) void*)(Bg + (size_t)p * 32 * K_TOT),
          (__attribute__((address_space(3))) void*)(Bsp + p * 2048), 16, 0, 0);
    Bg += 64;

    int if_nxt = if_cur; u64 en0 = e0, en1 = e1;
    if (k0 < K_BASE_OFF) {
      // spline window: zero own 32-col half, scatter prefetched PB entries
#pragma unroll
      for (int q = 0; q < 4; ++q) {
        int ch = hf * 4 + q;
        *(uintx4*)&As[rr_ * 64 + ((ch ^ rx7) << 3)] = (uintx4)0u;
      }
      int k0w = k0 + hf * 32;
      int i_last = (k0w + 31) / 36;
#pragma unroll
      for (int ii = 0; ii < 2; ++ii) {
        int i = if_cur + ii;
        if (i <= i_last) {
          u64 e = ii ? e1 : e0;
          u32 lo = (u32)e, hi = (u32)(e >> 32);
          int mc = (int)(hi >> 16);
          float f0 = b2f(lo & 0xFFFFu);
          float f1 = b2f(lo >> 16);
          float f2 = b2f(hi & 0xFFFFu);
          u16 bv[4] = {(u16)lo, (u16)(lo >> 16), (u16)hi, f2b(1.0f - f0 - f1 - f2)};
          int cb = i * 36 + mc - 3 - k0;   // local col of j=0 within 64-window
#pragma unroll
          for (int j = 0; j < 4; ++j) {
            int c = cb + j;
            bool ok = ((u32)(c - hf * 32) < 32u) && ((u32)(mc - 3 + j) < 35u);
            int addr = ok ? (rr_ * 64 + (((c >> 3) ^ rx7) << 3) + (c & 7)) : dummy;
            As[addr] = bv[j];
          }
        }
      }
      // prefetch PB for next iter if it is still a spline window
      int k0n = k0 + 64;
      if (k0n < K_BASE_OFF) {
        if_nxt = (k0n + hf * 32) / 36;
        en0 = PBrow[if_nxt];
        en1 = PBrow[if_nxt + 1];
      }
    } else {
      // base/linear window: full 64-col fill from x
      bool isBase = (k0 < K_LIN_OFF);
      int xb = isBase ? (k0 - K_BASE_OFF) : (k0 - K_LIN_OFF);
#pragma unroll
      for (int p = 0; p < 4; ++p) {
        int cid = t + 256 * p;       // (row, chunk)
        int row = cid >> 3, ch = cid & 7;
        const float* xp = &x[(size_t)(bm * 128 + row) * IN_F + xb + ch * 8];
        floatx4 v0 = *(const floatx4*)xp;
        floatx4 v1 = *(const floatx4*)(xp + 4);
        float f[8] = {v0.x, v0.y, v0.z, v0.w, v1.x, v1.y, v1.z, v1.w};
        u16 r[8];
#pragma unroll
        for (int j = 0; j < 8; ++j) {
          float vv = f[j];
          if (isBase) vv = vv / (1.0f + __expf(-vv));
          r[j] = f2b(vv);
        }
        *(short8*)(As + row * 64 + ((ch ^ (row & 7)) << 3)) = *(short8*)r;
      }
    }
    __syncthreads();   // As written + Bs landed (vmcnt drain overlapped by build)

    // MFMA phase
#pragma unroll
    for (int h = 0; h < 2; ++h) {
      short8 af[4], bf[4];
      int c = h * 4 + cq;
#pragma unroll
      for (int tm = 0; tm < 4; ++tm) {
        int row = wm * 64 + tm * 16 + mr;
        af[tm] = *(const short8*)&As[row * 64 + ((c ^ (row & 7)) << 3)];
      }
#pragma unroll
      for (int tn = 0; tn < 4; ++tn) {
        int row = wn * 64 + tn * 16 + mr;
        bf[tn] = *(const short8*)&Bs[row * 64 + ((c ^ (row & 7)) << 3)];
      }
#pragma unroll
      for (int tm = 0; tm < 4; ++tm)
#pragma unroll
        for (int tn = 0; tn < 4; ++tn)
          acc[tm][tn] = __builtin_amdgcn_mfma_f32_16x16x32_bf16(af[tm], bf[tn], acc[tm][tn], 0, 0, 0);
    }
    __syncthreads();   // MFMA reads done before next iter overwrites
    if_cur = if_nxt; e0 = en0; e1 = en1;
  }

  // ---- epilogue: direct coalesced bf16 partial store, fixed per-thread layout.
  u16* Pb = P + ((size_t)tile * SPLITS + ks) * 16384;
#pragma unroll
  for (int q = 0; q < 8; ++q) {
    int tm = q >> 1, tn0 = (q & 1) * 2;
    u16 r[8];
#pragma unroll
    for (int z = 0; z < 4; ++z) r[z] = f2b(acc[tm][tn0][z]);
#pragma unroll
    for (int z = 0; z < 4; ++z) r[4 + z] = f2b(acc[tm][tn0 + 1][z]);
    *(short8*)(Pb + q * 2048 + t * 8) = *(short8*)r;
  }
}

// ---- reduce 32 bf16 partial tiles + bias -> fp32 out (decodes C-layout)
__global__ __launch_bounds__(256) void reduce_kernel(const u16* __restrict__ P,
                                                     const float* __restrict__ bias_part,
                                                     float* __restrict__ out) {
  int rid = blockIdx.x * 256 + threadIdx.x;  // 65536 = tile*2048 + q*256 + t
  int tile = rid >> 11;
  int rem = rid & 2047;
  int q = rem >> 8, t = rem & 255;
  const u16* base = P + (size_t)tile * SPLITS * 16384 + q * 2048 + t * 8;

  float s[8] = {0, 0, 0, 0, 0, 0, 0, 0};
#pragma unroll
  for (int ks = 0; ks < SPLITS; ++ks) {
    short8 v = *(const short8*)(base + (size_t)ks * 16384);
#pragma unroll
    for (int j = 0; j < 8; ++j) s[j] += b2f((u32)(u16)v[j]);
  }

  int w = t >> 6, l = t & 63;
  int wm = w & 1, wn = w >> 1;
  int bm = tile >> 2, bn = tile & 3;
  int row0 = bm * 128 + wm * 64 + ((l >> 4) << 2);
  int col0 = bn * 128 + wn * 64 + (l & 15);
  int tm = q >> 1, tn0 = (q & 1) * 2;
#pragma unroll
  for (int j = 0; j < 8; ++j) {
    int tn = tn0 + (j >> 2), rr = j & 3;
    int row = row0 + tm * 16 + rr;
    int col = col0 + tn * 16;
    float bsv = bias_part[2 * col] + bias_part[2 * col + 1];
    out[(size_t)row * OUT_F + col] = s[j] + bsv;
  }
}

extern "C" void kernel_launch(void* const* d_in, const int* in_sizes, int n_in,
                              void* d_out, int out_size, void* d_ws, size_t ws_size,
                              hipStream_t stream) {
  const float* x  = (const float*)d_in[0];
  const float* bw = (const float*)d_in[1];
  const float* sw = (const float*)d_in[2];
  const float* sc = (const float*)d_in[3];
  // d_in[4] = grid: uniform h=1/16 extended knots, constants baked in.
  const void* mask = d_in[5];

  const size_t B_BYTES = (size_t)OUT_F * K_TOT * 2;         // 19,922,944
  const size_t BIAS_OFF = B_BYTES;                          // 1024 floats
  const size_t PB_OFF = B_BYTES + 8192;
  const size_t PB_BYTES = (size_t)MN * 8;                   // 4,194,304
  const size_t P_OFF = PB_OFF + PB_BYTES;                   // P: 33,554,432

  char* wsb = (char*)d_ws;
  u16* Bpack = (u16*)wsb;
  float* bias_part = (float*)(wsb + BIAS_OFF);
  u64* PB8 = (u64*)(wsb + PB_OFF);
  u16* P = (u16*)(wsb + P_OFF);

  prep_kernel<<<3072, 256, 0, stream>>>(bw, sw, sc, mask, x, Bpack, bias_part, PB8);
  gemm_fused<<<1024, 256, 0, stream>>>(x, PB8, Bpack, P);
  reduce_kernel<<<256, 256, 0, stream>>>(P, bias_part, (float*)d_out);
}